// Round 2
// baseline (2291.562 us; speedup 1.0000x reference)
//
#include <hip/hip_runtime.h>
#include <hip/hip_bf16.h>

#define N_NODES 10000
#define N_EDGES 640000
#define D 128

// ---------------------------------------------------------------------------
// Edge-index dtype probe: reference says int64, but the harness may ship int32.
// For row-major [2,E] int64 (little-endian), odd 32-bit words are high halves
// (ids < 10000 => zero). For int32 they are random node ids.
// flag = 1 -> int32 layout, flag = 0 -> int64 layout.
__global__ void detect_kernel(const void* ei, int* flag) {
    const int* p = (const int*)ei;
    bool nz = false;
    for (int it = 0; it < 16; ++it) {
        int i = 2 * (threadIdx.x + it * 256) + 1;   // odd words in [1, 8191]
        if (p[i] != 0) nz = true;
    }
    if (__any(nz) && (threadIdx.x & 63) == 0) flag[0] = 1;
}

__device__ __forceinline__ int edge_at(const void* ei, int is32, int idx) {
    if (is32) return ((const int*)ei)[idx];
    return (int)((const long long*)ei)[idx];
}

// ---------------------------------------------------------------------------
// deg[dst] += 1 per edge (float, reused by both layers)
__global__ void deg_kernel(const void* __restrict__ ei, const int* __restrict__ flag,
                           float* __restrict__ deg) {
    int e = blockIdx.x * 256 + threadIdx.x;
    if (e >= N_EDGES) return;
    int is32 = *flag;
    int dn = edge_at(ei, is32, N_EDGES + e);
    atomicAdd(&deg[dn], 1.0f);
}

// ---------------------------------------------------------------------------
// agg[dst, :] += x[src, :]  — 32 threads per edge, float4 per thread.
// grid = N_EDGES*32/256 = 80000 blocks.
__global__ void scatter_kernel(const float* __restrict__ x, const void* __restrict__ ei,
                               const int* __restrict__ flag, float* __restrict__ agg) {
    unsigned int t = blockIdx.x * 256u + threadIdx.x;
    int e = (int)(t >> 5);        // edge index
    int c = (int)(t & 31u);       // 4-dim chunk within the row
    if (e >= N_EDGES) return;
    int is32 = *flag;
    int s  = edge_at(ei, is32, e);
    int dn = edge_at(ei, is32, N_EDGES + e);
    const float4 v = ((const float4*)(x + (size_t)s * D))[c];
    float* a = agg + (size_t)dn * D + c * 4;
    atomicAdd(a + 0, v.x);
    atomicAdd(a + 1, v.y);
    atomicAdd(a + 2, v.z);
    atomicAdd(a + 3, v.w);
}

// ---------------------------------------------------------------------------
// out[i,:] = ELU( (agg[i,:]/max(deg[i],1)) @ Wl + b + x[i,:] @ Wr )
// one block (128 threads) per node; thread d owns output column d.
__global__ void sage_layer_kernel(const float* __restrict__ x, const float* __restrict__ agg,
                                  const float* __restrict__ deg,
                                  const float* __restrict__ Wl, const float* __restrict__ b,
                                  const float* __restrict__ Wr, float* __restrict__ out) {
    int i = blockIdx.x;
    int d = threadIdx.x;
    __shared__ float xs[D];
    __shared__ float as[D];
    float invd = 1.0f / fmaxf(deg[i], 1.0f);
    xs[d] = x[(size_t)i * D + d];
    as[d] = agg[(size_t)i * D + d] * invd;
    __syncthreads();
    float acc = b[d];
#pragma unroll 8
    for (int k = 0; k < D; ++k) {
        acc += as[k] * Wl[k * D + d] + xs[k] * Wr[k * D + d];
    }
    out[(size_t)i * D + d] = acc > 0.0f ? acc : expm1f(acc);   // ELU alpha=1
}

// ---------------------------------------------------------------------------
extern "C" void kernel_launch(void* const* d_in, const int* in_sizes, int n_in,
                              void* d_out, int out_size, void* d_ws, size_t ws_size,
                              hipStream_t stream) {
    const float* x   = (const float*)d_in[0];
    const void*  ei  = d_in[1];
    const float* Wl0 = (const float*)d_in[2];
    const float* b0  = (const float*)d_in[3];
    const float* Wr0 = (const float*)d_in[4];
    const float* Wl1 = (const float*)d_in[5];
    const float* b1  = (const float*)d_in[6];
    const float* Wr1 = (const float*)d_in[7];
    float* out = (float*)d_out;

    char* ws = (char*)d_ws;
    int*   flag = (int*)ws;                      // offset 0
    float* deg  = (float*)(ws + 256);            // 10000 floats
    float* agg  = (float*)(ws + 64 * 1024);      // N*D floats = 5.12 MB

    const size_t zero_bytes = 64 * 1024 + (size_t)N_NODES * D * sizeof(float);
    hipMemsetAsync(ws, 0, zero_bytes, stream);   // flag + deg + agg

    detect_kernel<<<1, 256, 0, stream>>>(ei, flag);
    deg_kernel<<<(N_EDGES + 255) / 256, 256, 0, stream>>>(ei, flag, deg);

    const int scatter_blocks = (N_EDGES * 32) / 256;   // 80000
    // layer 0
    scatter_kernel<<<scatter_blocks, 256, 0, stream>>>(x, ei, flag, agg);
    sage_layer_kernel<<<N_NODES, D, 0, stream>>>(x, agg, deg, Wl0, b0, Wr0, out);

    // layer 1 (aggregate from layer-0 output, write in place)
    hipMemsetAsync(agg, 0, (size_t)N_NODES * D * sizeof(float), stream);
    scatter_kernel<<<scatter_blocks, 256, 0, stream>>>(out, ei, flag, agg);
    sage_layer_kernel<<<N_NODES, D, 0, stream>>>(out, agg, deg, Wl1, b1, Wr1, out);
}

// Round 3
// 242.307 us; speedup vs baseline: 9.4573x; 9.4573x over previous
//
#include <hip/hip_runtime.h>
#include <hip/hip_bf16.h>

#define N_NODES 10000
#define N_EDGES 640000
#define D 128

// ---------------------------------------------------------------------------
// Edge-index dtype probe (int64 vs int32, see R0 notes). flag=1 -> int32.
__global__ void detect_kernel(const void* ei, int* flag) {
    const int* p = (const int*)ei;
    bool nz = false;
    for (int it = 0; it < 16; ++it) {
        int i = 2 * (threadIdx.x + it * 256) + 1;   // odd words in [1, 8191]
        if (p[i] != 0) nz = true;
    }
    if (__any(nz) && (threadIdx.x & 63) == 0) flag[0] = 1;
}

__device__ __forceinline__ int edge_at(const void* ei, int is32, int idx) {
    if (is32) return ((const int*)ei)[idx];
    return (int)((const long long*)ei)[idx];
}

// ---------------------------------------------------------------------------
// int degree histogram over dst
__global__ void deg_kernel(const void* __restrict__ ei, const int* __restrict__ flag,
                           int* __restrict__ deg) {
    int e = blockIdx.x * 256 + threadIdx.x;
    if (e >= N_EDGES) return;
    int is32 = *flag;
    int dn = edge_at(ei, is32, N_EDGES + e);
    atomicAdd(&deg[dn], 1);
}

// ---------------------------------------------------------------------------
// exclusive prefix scan: row_start[i] = sum(deg[0..i-1]), row_start[N]=E
__global__ void scan_kernel(const int* __restrict__ deg, int* __restrict__ row_start) {
    __shared__ int lsum[256];
    __shared__ int lpre[257];
    int t = threadIdx.x;
    const int CH = 40;                     // 256*40 = 10240 >= N_NODES+1
    int base = t * CH;
    int s = 0;
    for (int k = 0; k < CH; ++k) { int i = base + k; if (i < N_NODES) s += deg[i]; }
    lsum[t] = s;
    __syncthreads();
    if (t == 0) {
        int c = 0;
        for (int u = 0; u < 256; ++u) { lpre[u] = c; c += lsum[u]; }
        lpre[256] = c;
    }
    __syncthreads();
    int run = lpre[t];
    for (int k = 0; k < CH; ++k) {
        int i = base + k;
        if (i <= N_NODES) {
            row_start[i] = run;
            if (i < N_NODES) run += deg[i];
        }
    }
}

// ---------------------------------------------------------------------------
// CSR fill: adj[row_start[dst] + cursor[dst]++] = src
__global__ void fill_kernel(const void* __restrict__ ei, const int* __restrict__ flag,
                            const int* __restrict__ row_start, int* __restrict__ cursor,
                            int* __restrict__ adj) {
    int e = blockIdx.x * 256 + threadIdx.x;
    if (e >= N_EDGES) return;
    int is32 = *flag;
    int s  = edge_at(ei, is32, e);
    int dn = edge_at(ei, is32, N_EDGES + e);
    int pos = atomicAdd(&cursor[dn], 1);
    adj[row_start[dn] + pos] = s;
}

// ---------------------------------------------------------------------------
// agg[i,:] = mean over neighbors j of xin[j,:]   (block per node, thread = col)
__global__ void gather_kernel(const float* __restrict__ xin, const int* __restrict__ adj,
                              const int* __restrict__ row_start, float* __restrict__ agg) {
    int i = blockIdx.x;
    int d = threadIdx.x;
    int beg = row_start[i], end = row_start[i + 1];
    float acc = 0.0f;
    int p = beg;
    for (; p + 4 <= end; p += 4) {
        int j0 = adj[p], j1 = adj[p + 1], j2 = adj[p + 2], j3 = adj[p + 3];
        float v0 = xin[(size_t)j0 * D + d];
        float v1 = xin[(size_t)j1 * D + d];
        float v2 = xin[(size_t)j2 * D + d];
        float v3 = xin[(size_t)j3 * D + d];
        acc += v0 + v1 + v2 + v3;
    }
    for (; p < end; ++p) acc += xin[(size_t)adj[p] * D + d];
    float cnt = (float)(end - beg);
    agg[(size_t)i * D + d] = acc / fmaxf(cnt, 1.0f);
}

// ---------------------------------------------------------------------------
// out[i,:] = ELU(agg[i,:] @ Wl + b + x[i,:] @ Wr)  — 32 nodes/block, 256 thr.
#define NT 32
__global__ __launch_bounds__(256)
void gemm_kernel(const float* __restrict__ x, const float* __restrict__ agg,
                 const float* __restrict__ Wl, const float* __restrict__ b,
                 const float* __restrict__ Wr, float* __restrict__ out) {
    __shared__ float as_[NT][D];
    __shared__ float xs_[NT][D];
    const int nb = blockIdx.x * NT;
    const int t  = threadIdx.x;

    // cooperative load of NT rows of agg and x (float4, coalesced)
    float4*       asf4 = (float4*)&as_[0][0];
    float4*       xsf4 = (float4*)&xs_[0][0];
    const float4* af4  = (const float4*)(agg + (size_t)nb * D);
    const float4* xf4  = (const float4*)(x   + (size_t)nb * D);
    const int nvalid4 = (N_NODES - nb) * (D / 4);       // valid float4 count
#pragma unroll
    for (int q = 0; q < (NT * D / 4) / 256; ++q) {      // 4 iterations
        int idx = t + q * 256;
        float4 av = make_float4(0.f, 0.f, 0.f, 0.f), xv = av;
        if (idx < nvalid4) { av = af4[idx]; xv = xf4[idx]; }
        asf4[idx] = av;
        xsf4[idx] = xv;
    }
    __syncthreads();

    const int d = t & 127;          // output column
    const int h = t >> 7;           // node half: 0 or 1
    float acc[NT / 2];
#pragma unroll
    for (int n = 0; n < NT / 2; ++n) acc[n] = 0.0f;

    const float4* asq = (const float4*)&as_[h * (NT / 2)][0];
    const float4* xsq = (const float4*)&xs_[h * (NT / 2)][0];

    for (int k4 = 0; k4 < D / 4; ++k4) {
        float wl0 = Wl[(k4 * 4 + 0) * D + d];
        float wl1 = Wl[(k4 * 4 + 1) * D + d];
        float wl2 = Wl[(k4 * 4 + 2) * D + d];
        float wl3 = Wl[(k4 * 4 + 3) * D + d];
        float wr0 = Wr[(k4 * 4 + 0) * D + d];
        float wr1 = Wr[(k4 * 4 + 1) * D + d];
        float wr2 = Wr[(k4 * 4 + 2) * D + d];
        float wr3 = Wr[(k4 * 4 + 3) * D + d];
#pragma unroll
        for (int n = 0; n < NT / 2; ++n) {
            float4 a4 = asq[n * (D / 4) + k4];
            float4 x4 = xsq[n * (D / 4) + k4];
            acc[n] += a4.x * wl0 + a4.y * wl1 + a4.z * wl2 + a4.w * wl3
                    + x4.x * wr0 + x4.y * wr1 + x4.z * wr2 + x4.w * wr3;
        }
    }

    float bias = b[d];
#pragma unroll
    for (int n = 0; n < NT / 2; ++n) {
        int node = nb + h * (NT / 2) + n;
        if (node < N_NODES) {
            float v = acc[n] + bias;
            out[(size_t)node * D + d] = v > 0.0f ? v : expm1f(v);  // ELU alpha=1
        }
    }
}

// ---------------------------------------------------------------------------
extern "C" void kernel_launch(void* const* d_in, const int* in_sizes, int n_in,
                              void* d_out, int out_size, void* d_ws, size_t ws_size,
                              hipStream_t stream) {
    const float* x   = (const float*)d_in[0];
    const void*  ei  = d_in[1];
    const float* Wl0 = (const float*)d_in[2];
    const float* b0  = (const float*)d_in[3];
    const float* Wr0 = (const float*)d_in[4];
    const float* Wl1 = (const float*)d_in[5];
    const float* b1  = (const float*)d_in[6];
    const float* Wr1 = (const float*)d_in[7];
    float* out = (float*)d_out;

    char* ws = (char*)d_ws;
    int*   flag      = (int*)(ws + 0);
    int*   deg       = (int*)(ws + 1024);        // 40000 B
    int*   row_start = (int*)(ws + 65536);       // 40004 B
    int*   cursor    = (int*)(ws + 131072);      // 40000 B
    int*   adj       = (int*)(ws + 262144);      // 2.56 MB
    float* agg       = (float*)(ws + 4194304);   // 5.12 MB

    // zero flag + deg + cursor (row_start/adj/agg fully overwritten)
    hipMemsetAsync(ws, 0, 171072, stream);

    detect_kernel<<<1, 256, 0, stream>>>(ei, flag);
    deg_kernel<<<(N_EDGES + 255) / 256, 256, 0, stream>>>(ei, flag, deg);
    scan_kernel<<<1, 256, 0, stream>>>(deg, row_start);
    fill_kernel<<<(N_EDGES + 255) / 256, 256, 0, stream>>>(ei, flag, row_start, cursor, adj);

    const int gemm_grid = (N_NODES + NT - 1) / NT;   // 313
    // layer 0
    gather_kernel<<<N_NODES, D, 0, stream>>>(x, adj, row_start, agg);
    gemm_kernel<<<gemm_grid, 256, 0, stream>>>(x, agg, Wl0, b0, Wr0, out);
    // layer 1 (in place)
    gather_kernel<<<N_NODES, D, 0, stream>>>(out, adj, row_start, agg);
    gemm_kernel<<<gemm_grid, 256, 0, stream>>>(out, agg, Wl1, b1, Wr1, out);
}